// Round 1
// baseline (536.905 us; speedup 1.0000x reference)
//
#include <hip/hip_runtime.h>
#include <hip/hip_bf16.h>

#define HID 128
#define LMD 1024
#define BGR 64
#define NPG 501
#define NN (BGR*NPG)
#define NRELT 42
#define NEG 0.2f

// te[r] = edge_table[r] . (W_edge @ att_edge)
__global__ void k_pre(const float* __restrict__ W_edge, const float* __restrict__ att_edge,
                      const float* __restrict__ edge_table, float* __restrict__ te){
  __shared__ float we[HID];
  int t = threadIdx.x;
  if (t < HID){
    float s = 0.f;
    for (int j=0;j<HID;++j) s += W_edge[t*HID+j]*att_edge[j];
    we[t] = s;
  }
  __syncthreads();
  if (t < NRELT){
    float s = 0.f;
    for (int i=0;i<HID;++i) s += edge_table[t*HID+i]*we[i];
    te[t] = s;
  }
}

// ctx_emb = lm @ W_lm + b_lm
__global__ void k_ctx(const float* __restrict__ lm, const float* __restrict__ W_lm,
                      const float* __restrict__ b_lm, float* __restrict__ ctx_emb){
  int b = blockIdx.x, h = threadIdx.x;
  const float* lr = lm + (size_t)b*LMD;
  float s = b_lm[h];
  for (int l=0;l<LMD;++l) s += lr[l]*W_lm[(size_t)l*HID + h];
  ctx_emb[b*HID + h] = s;
}

__global__ void k_zero(int* __restrict__ deg, float* __restrict__ asum, int* __restrict__ counter){
  int i = blockIdx.x*256 + threadIdx.x;
  if (i < NN){ deg[i]=0; asum[i]=0.f; }
  if (i == 0) counter[0]=0;
}

__global__ void k_count(const int* __restrict__ dst, const int* __restrict__ et,
                        const float* __restrict__ te, int* __restrict__ deg,
                        float* __restrict__ asum, int E){
  int e = blockIdx.x*256 + threadIdx.x;
  if (e >= E) return;
  int d = dst[e];
  atomicAdd(&deg[d], 1);
  atomicAdd(&asum[d], te[et[e]]);
}

__global__ void k_offsets(const int* __restrict__ deg, const float* __restrict__ asum,
                          int* __restrict__ off, int* __restrict__ cursor,
                          float* __restrict__ aself, int* __restrict__ counter){
  int i = blockIdx.x*256 + threadIdx.x;
  if (i >= NN) return;
  int d = deg[i];
  int o = atomicAdd(counter, d);
  off[i] = o; cursor[i] = o;
  aself[i] = asum[i] / (float)(d > 1 ? d : 1);
}

__global__ void k_fill(const int* __restrict__ src, const int* __restrict__ dst,
                       const int* __restrict__ et, const float* __restrict__ te,
                       int* __restrict__ cursor, int* __restrict__ csr_src,
                       float* __restrict__ csr_aed, int E){
  int e = blockIdx.x*256 + threadIdx.x;
  if (e >= E) return;
  int d = dst[e];
  int pos = atomicAdd(&cursor[d], 1);
  csr_src[pos] = src[e];
  csr_aed[pos] = te[et[e]];
}

// tmp[lh][b][k][h] partial over l-halves: tmp[b,k,h] = sum_l lm[b,l]*W_bil[k,l,h]
__global__ __launch_bounds__(256) void k_tmp(const float* __restrict__ lm,
                                             const float* __restrict__ W_bil,
                                             float* __restrict__ tmp){
  const int bid = blockIdx.x;
  const int k  = bid >> 2;
  const int h0 = ((bid >> 1) & 1) * 64;
  const int lbase = (bid & 1) * 512;
  __shared__ float As[32][65];
  __shared__ float Bs[32][64];
  const int tid = threadIdx.x;
  const int ty = tid >> 4, tx = tid & 15;
  float acc[4][4] = {};
  const float* __restrict__ Wk = W_bil + (size_t)k*LMD*HID;
  const int ar = tid >> 2, ac = (tid & 3) * 8;   // b, l-off
  const int br = tid >> 3, bc = (tid & 7) * 8;   // lc, h-off
  for (int l0 = 0; l0 < 512; l0 += 32){
    const int l = lbase + l0;
    #pragma unroll
    for (int j=0;j<8;++j) As[ac+j][ar] = lm[(size_t)ar*LMD + l + ac + j];
    #pragma unroll
    for (int j=0;j<8;++j) Bs[br][bc+j] = Wk[(size_t)(l + br)*HID + h0 + bc + j];
    __syncthreads();
    #pragma unroll
    for (int lc=0; lc<32; ++lc){
      float a[4], b[4];
      #pragma unroll
      for (int i=0;i<4;++i) a[i] = As[lc][ty*4+i];
      #pragma unroll
      for (int j=0;j<4;++j) b[j] = Bs[lc][tx*4+j];
      #pragma unroll
      for (int i=0;i<4;++i)
        #pragma unroll
        for (int j=0;j<4;++j) acc[i][j] += a[i]*b[j];
    }
    __syncthreads();
  }
  const size_t part = (size_t)(bid & 1) * (BGR*HID*HID);
  #pragma unroll
  for (int i=0;i<4;++i){
    int b = ty*4+i;
    float* o = tmp + part + ((size_t)b*HID + k)*HID + h0 + tx*4;
    #pragma unroll
    for (int j=0;j<4;++j) o[j] = acc[i][j];
  }
}

// nodes[g*NPG+n, k] = sum_h tmp[g,k,h]*x[g,n,h] + b_bil[k]  (x row 0 = ctx_emb)
__global__ __launch_bounds__(256) void k_apply(const float* __restrict__ node_emb,
                                               const float* __restrict__ ctx_emb,
                                               const float* __restrict__ tmp,
                                               const float* __restrict__ b_bil,
                                               float* __restrict__ nodes){
  const int bid = blockIdx.x;
  const int g  = bid >> 4;
  const int rt = (bid >> 1) & 7;
  const int kt = bid & 1;
  const int n0 = rt*64, k0 = kt*64;
  __shared__ float As[32][65];
  __shared__ float Bs[32][65];
  const int tid = threadIdx.x, ty = tid>>4, tx = tid&15;
  float acc[4][4] = {};
  const int lr = tid >> 2, lc = (tid & 3) * 8;
  const float* xrow = nullptr;
  {
    int nl = n0 + lr;
    if (nl < NPG) xrow = (nl == 0) ? (ctx_emb + (size_t)g*HID)
                                   : (node_emb + ((size_t)(g*NPG + nl))*HID);
  }
  const float* pA = tmp + ((size_t)(g*HID + k0 + lr))*HID;
  const float* pB = pA + (size_t)BGR*HID*HID;
  for (int h0c = 0; h0c < HID; h0c += 32){
    #pragma unroll
    for (int j=0;j<8;++j) As[lc+j][lr] = xrow ? xrow[h0c + lc + j] : 0.f;
    #pragma unroll
    for (int j=0;j<8;++j) Bs[lc+j][lr] = pA[h0c+lc+j] + pB[h0c+lc+j];
    __syncthreads();
    #pragma unroll
    for (int hc=0;hc<32;++hc){
      float a[4], b[4];
      #pragma unroll
      for (int i=0;i<4;++i) a[i] = As[hc][ty*4+i];
      #pragma unroll
      for (int j=0;j<4;++j) b[j] = Bs[hc][tx*4+j];
      #pragma unroll
      for (int i=0;i<4;++i)
        #pragma unroll
        for (int j=0;j<4;++j) acc[i][j] += a[i]*b[j];
    }
    __syncthreads();
  }
  float bb[4];
  #pragma unroll
  for (int j=0;j<4;++j) bb[j] = b_bil[k0 + tx*4 + j];
  #pragma unroll
  for (int i=0;i<4;++i){
    int nl = n0 + ty*4 + i;
    if (nl < NPG){
      float* o = nodes + ((size_t)(g*NPG + nl))*HID + k0 + tx*4;
      #pragma unroll
      for (int j=0;j<4;++j) o[j] = acc[i][j] + bb[j];
    }
  }
}

// xl = nodes @ W_gat ; as = xl.att_src ; ad = xl.att_dst (fused epilogue)
__global__ __launch_bounds__(256) void k_xl(const float* __restrict__ nodes,
                                            const float* __restrict__ W_gat,
                                            const float* __restrict__ att_src,
                                            const float* __restrict__ att_dst,
                                            float* __restrict__ xl,
                                            float* __restrict__ as_a,
                                            float* __restrict__ ad_a){
  const int n0 = blockIdx.x * 64;
  __shared__ float As[32][65];
  __shared__ float Bs[32][128];
  __shared__ float reds[64][17];
  __shared__ float redd[64][17];
  const int tid = threadIdx.x, ty = tid>>4, tx = tid&15;
  float acc[4][8] = {};
  const int ar = tid>>2, ac = (tid&3)*8;
  const int br = tid>>3, bc = (tid&7)*16;
  for (int k0=0;k0<HID;k0+=32){
    #pragma unroll
    for (int j=0;j<8;++j) As[ac+j][ar] = nodes[(size_t)(n0+ar)*HID + k0+ac+j];
    #pragma unroll
    for (int j=0;j<16;++j) Bs[br][bc+j] = W_gat[(size_t)(k0+br)*HID + bc + j];
    __syncthreads();
    #pragma unroll
    for (int kc=0;kc<32;++kc){
      float a[4], b[8];
      #pragma unroll
      for (int i=0;i<4;++i) a[i] = As[kc][ty*4+i];
      #pragma unroll
      for (int j=0;j<8;++j) b[j] = Bs[kc][tx*8+j];
      #pragma unroll
      for (int i=0;i<4;++i)
        #pragma unroll
        for (int j=0;j<8;++j) acc[i][j] += a[i]*b[j];
    }
    __syncthreads();
  }
  float asr[8], adr[8];
  #pragma unroll
  for (int j=0;j<8;++j){ asr[j]=att_src[tx*8+j]; adr[j]=att_dst[tx*8+j]; }
  #pragma unroll
  for (int i=0;i<4;++i){
    float ps=0.f, pd=0.f;
    #pragma unroll
    for (int j=0;j<8;++j){ ps += acc[i][j]*asr[j]; pd += acc[i][j]*adr[j]; }
    reds[ty*4+i][tx]=ps; redd[ty*4+i][tx]=pd;
    float4 v0 = make_float4(acc[i][0],acc[i][1],acc[i][2],acc[i][3]);
    float4 v1 = make_float4(acc[i][4],acc[i][5],acc[i][6],acc[i][7]);
    float* o = xl + (size_t)(n0+ty*4+i)*HID + tx*8;
    *(float4*)o = v0; *(float4*)(o+4) = v1;
  }
  __syncthreads();
  if (tid < 64){
    float s=0.f, d2=0.f;
    #pragma unroll
    for (int t2=0;t2<16;++t2){ s += reds[tid][t2]; d2 += redd[tid][t2]; }
    as_a[n0+tid]=s; ad_a[n0+tid]=d2;
  }
}

// per-node softmax-weighted aggregation (1 wave per node), self-loop included
__global__ __launch_bounds__(256) void k_agg(const float* __restrict__ xl,
                                             const float* __restrict__ as_a,
                                             const float* __restrict__ ad_a,
                                             const float* __restrict__ aself,
                                             const int* __restrict__ off,
                                             const int* __restrict__ deg,
                                             const int* __restrict__ csr_src,
                                             const float* __restrict__ csr_aed,
                                             const float* __restrict__ gbias,
                                             float* __restrict__ nodes){
  const int lane = threadIdx.x & 63;
  const int n = blockIdx.x*4 + (threadIdx.x >> 6);
  if (n >= NN) return;
  const int o = off[n], d = deg[n];
  const float ad_n = ad_a[n];
  float a_self = as_a[n] + ad_n + aself[n];
  a_self = a_self > 0.f ? a_self : a_self*NEG;
  float m = -1e30f, s = 0.f;
  for (int i = lane; i < d; i += 64){
    int si = csr_src[o+i];
    float a = as_a[si] + ad_n + csr_aed[o+i];
    a = a > 0.f ? a : a*NEG;
    if (a > m){ s = s*__expf(m - a) + 1.f; m = a; }
    else s += __expf(a - m);
  }
  #pragma unroll
  for (int w=32; w>=1; w>>=1){
    float mo = __shfl_xor(m, w);
    float so = __shfl_xor(s, w);
    float M = fmaxf(m, mo);
    s = s*__expf(m - M) + so*__expf(mo - M);
    m = M;
  }
  { float M = fmaxf(m, a_self);
    s = s*__expf(m - M) + __expf(a_self - M);
    m = M; }
  const float inv = 1.f / s;
  float accx = 0.f, accy = 0.f;
  for (int i = 0; i < d; ++i){
    int si = csr_src[o+i];
    float a = as_a[si] + ad_n + csr_aed[o+i];
    a = a > 0.f ? a : a*NEG;
    float w = __expf(a - m)*inv;
    const float2 v = *(const float2*)(xl + (size_t)si*HID + lane*2);
    accx += w*v.x; accy += w*v.y;
  }
  { float w = __expf(a_self - m)*inv;
    const float2 v = *(const float2*)(xl + (size_t)n*HID + lane*2);
    accx += w*v.x; accy += w*v.y; }
  float2 ov;
  ov.x = accx + gbias[lane*2];
  ov.y = accy + gbias[lane*2+1];
  *(float2*)(nodes + (size_t)n*HID + lane*2) = ov;
}

__global__ void k_out(const float* __restrict__ nodes, const int* __restrict__ ctxn,
                      float* __restrict__ out){
  int b = blockIdx.x, h = threadIdx.x;
  out[b*HID + h] = nodes[(size_t)ctxn[b]*HID + h];
}

extern "C" void kernel_launch(void* const* d_in, const int* in_sizes, int n_in,
                              void* d_out, int out_size, void* d_ws, size_t ws_size,
                              hipStream_t stream){
  (void)n_in; (void)out_size; (void)ws_size;
  const float* lm       = (const float*)d_in[0];
  const float* node_emb = (const float*)d_in[1];
  const int*   eidx     = (const int*)d_in[2];
  const int*   etype    = (const int*)d_in[3];
  const int*   ctxn     = (const int*)d_in[4];
  const float* W_lm     = (const float*)d_in[5];
  const float* b_lm     = (const float*)d_in[6];
  const float* W_bil    = (const float*)d_in[7];
  const float* b_bil    = (const float*)d_in[8];
  const float* etab     = (const float*)d_in[9];
  const float* W_gat    = (const float*)d_in[10];
  const float* att_src  = (const float*)d_in[11];
  const float* att_dst  = (const float*)d_in[12];
  const float* W_edge   = (const float*)d_in[13];
  const float* att_edge = (const float*)d_in[14];
  const float* gbias    = (const float*)d_in[15];
  const int E = in_sizes[3];
  const int* src = eidx;
  const int* dst = eidx + E;

  char* p = (char*)d_ws;
  auto take = [&](size_t nbytes){ void* r = (void*)p; p += (nbytes + 255) & ~(size_t)255; return r; };
  float* nodes   = (float*)take((size_t)NN*HID*4);
  float* xl      = (float*)take((size_t)NN*HID*4);
  float* tmp     = (float*)take((size_t)2*BGR*HID*HID*4);
  float* ctx_emb = (float*)take((size_t)BGR*HID*4);
  float* as_a    = (float*)take((size_t)NN*4);
  float* ad_a    = (float*)take((size_t)NN*4);
  float* aself   = (float*)take((size_t)NN*4);
  float* asum    = (float*)take((size_t)NN*4);
  int*   deg     = (int*)take((size_t)NN*4);
  int*   off     = (int*)take((size_t)NN*4);
  int*   cursor  = (int*)take((size_t)NN*4);
  int*   counter = (int*)take(256);
  float* te      = (float*)take(256);
  int*   csr_src = (int*)take((size_t)E*4);
  float* csr_aed = (float*)take((size_t)E*4);

  k_pre<<<1,128,0,stream>>>(W_edge, att_edge, etab, te);
  k_ctx<<<BGR,HID,0,stream>>>(lm, W_lm, b_lm, ctx_emb);
  k_zero<<<(NN+255)/256,256,0,stream>>>(deg, asum, counter);
  k_count<<<(E+255)/256,256,0,stream>>>(dst, etype, te, deg, asum, E);
  k_offsets<<<(NN+255)/256,256,0,stream>>>(deg, asum, off, cursor, aself, counter);
  k_fill<<<(E+255)/256,256,0,stream>>>(src, dst, etype, te, cursor, csr_src, csr_aed, E);
  k_tmp<<<512,256,0,stream>>>(lm, W_bil, tmp);
  k_apply<<<BGR*16,256,0,stream>>>(node_emb, ctx_emb, tmp, b_bil, nodes);
  for (int h=0; h<3; ++h){
    k_xl<<<NN/64,256,0,stream>>>(nodes, W_gat, att_src, att_dst, xl, as_a, ad_a);
    k_agg<<<NN/4,256,0,stream>>>(xl, as_a, ad_a, aself, off, deg, csr_src, csr_aed, gbias, nodes);
  }
  k_out<<<BGR,HID,0,stream>>>(nodes, ctxn, (float*)d_out);
}

// Round 2
// 445.722 us; speedup vs baseline: 1.2046x; 1.2046x over previous
//
#include <hip/hip_runtime.h>
#include <hip/hip_bf16.h>

#define HID 128
#define LMD 1024
#define BGR 64
#define NPG 501
#define NN (BGR*NPG)
#define NRELT 42
#define NEG 0.2f

// te[r] = edge_table[r] . (W_edge @ att_edge)
__global__ void k_pre(const float* __restrict__ W_edge, const float* __restrict__ att_edge,
                      const float* __restrict__ edge_table, float* __restrict__ te){
  __shared__ float we[HID];
  int t = threadIdx.x;
  if (t < HID){
    float s = 0.f;
    for (int j=0;j<HID;++j) s += W_edge[t*HID+j]*att_edge[j];
    we[t] = s;
  }
  __syncthreads();
  if (t < NRELT){
    float s = 0.f;
    for (int i=0;i<HID;++i) s += edge_table[t*HID+i]*we[i];
    te[t] = s;
  }
}

// ctx_emb = lm @ W_lm + b_lm
__global__ void k_ctx(const float* __restrict__ lm, const float* __restrict__ W_lm,
                      const float* __restrict__ b_lm, float* __restrict__ ctx_emb){
  int b = blockIdx.x, h = threadIdx.x;
  const float* lr = lm + (size_t)b*LMD;
  float s = b_lm[h];
  for (int l=0;l<LMD;++l) s += lr[l]*W_lm[(size_t)l*HID + h];
  ctx_emb[b*HID + h] = s;
}

__global__ void k_zero(int* __restrict__ deg, float* __restrict__ asum, int* __restrict__ counter){
  int i = blockIdx.x*256 + threadIdx.x;
  if (i < NN){ deg[i]=0; asum[i]=0.f; }
  if (i == 0) counter[0]=0;
}

__global__ void k_count(const int* __restrict__ dst, const int* __restrict__ et,
                        const float* __restrict__ te, int* __restrict__ deg,
                        float* __restrict__ asum, int E){
  int e = blockIdx.x*256 + threadIdx.x;
  if (e >= E) return;
  int d = dst[e];
  atomicAdd(&deg[d], 1);
  atomicAdd(&asum[d], te[et[e]]);
}

__global__ void k_offsets(const int* __restrict__ deg, const float* __restrict__ asum,
                          int* __restrict__ off, int* __restrict__ cursor,
                          float* __restrict__ aself, int* __restrict__ counter){
  int i = blockIdx.x*256 + threadIdx.x;
  if (i >= NN) return;
  int d = deg[i];
  int o = atomicAdd(counter, d);
  off[i] = o; cursor[i] = o;
  aself[i] = asum[i] / (float)(d > 1 ? d : 1);
}

__global__ void k_fill(const int* __restrict__ src, const int* __restrict__ dst,
                       const int* __restrict__ et, const float* __restrict__ te,
                       int* __restrict__ cursor, int* __restrict__ csr_src,
                       float* __restrict__ csr_aed, int E){
  int e = blockIdx.x*256 + threadIdx.x;
  if (e >= E) return;
  int d = dst[e];
  int pos = atomicAdd(&cursor[d], 1);
  csr_src[pos] = src[e];
  csr_aed[pos] = te[et[e]];
}

// tmp[lh][b][k][h] partial over l-halves: tmp[b,k,h] = sum_l lm[b,l]*W_bil[k,l,h]
__global__ __launch_bounds__(256) void k_tmp(const float* __restrict__ lm,
                                             const float* __restrict__ W_bil,
                                             float* __restrict__ tmp){
  const int bid = blockIdx.x;
  const int k  = bid >> 2;
  const int h0 = ((bid >> 1) & 1) * 64;
  const int lbase = (bid & 1) * 512;
  __shared__ float As[32][65];
  __shared__ float Bs[32][64];
  const int tid = threadIdx.x;
  const int ty = tid >> 4, tx = tid & 15;
  float acc[4][4] = {};
  const float* __restrict__ Wk = W_bil + (size_t)k*LMD*HID;
  const int ar = tid >> 2, ac = (tid & 3) * 8;   // b, l-off
  const int br = tid >> 3, bc = (tid & 7) * 8;   // lc, h-off
  for (int l0 = 0; l0 < 512; l0 += 32){
    const int l = lbase + l0;
    #pragma unroll
    for (int j=0;j<8;++j) As[ac+j][ar] = lm[(size_t)ar*LMD + l + ac + j];
    #pragma unroll
    for (int j=0;j<8;++j) Bs[br][bc+j] = Wk[(size_t)(l + br)*HID + h0 + bc + j];
    __syncthreads();
    #pragma unroll
    for (int lc=0; lc<32; ++lc){
      float a[4], b[4];
      #pragma unroll
      for (int i=0;i<4;++i) a[i] = As[lc][ty*4+i];
      #pragma unroll
      for (int j=0;j<4;++j) b[j] = Bs[lc][tx*4+j];
      #pragma unroll
      for (int i=0;i<4;++i)
        #pragma unroll
        for (int j=0;j<4;++j) acc[i][j] += a[i]*b[j];
    }
    __syncthreads();
  }
  const size_t part = (size_t)(bid & 1) * (BGR*HID*HID);
  #pragma unroll
  for (int i=0;i<4;++i){
    int b = ty*4+i;
    float* o = tmp + part + ((size_t)b*HID + k)*HID + h0 + tx*4;
    #pragma unroll
    for (int j=0;j<4;++j) o[j] = acc[i][j];
  }
}

// nodes[g*NPG+n, k] = sum_h tmp[g,k,h]*x[g,n,h] + b_bil[k]  (x row 0 = ctx_emb)
__global__ __launch_bounds__(256) void k_apply(const float* __restrict__ node_emb,
                                               const float* __restrict__ ctx_emb,
                                               const float* __restrict__ tmp,
                                               const float* __restrict__ b_bil,
                                               float* __restrict__ nodes){
  const int bid = blockIdx.x;
  const int g  = bid >> 4;
  const int rt = (bid >> 1) & 7;
  const int kt = bid & 1;
  const int n0 = rt*64, k0 = kt*64;
  __shared__ float As[32][65];
  __shared__ float Bs[32][65];
  const int tid = threadIdx.x, ty = tid>>4, tx = tid&15;
  float acc[4][4] = {};
  const int lr = tid >> 2, lc = (tid & 3) * 8;
  const float* xrow = nullptr;
  {
    int nl = n0 + lr;
    if (nl < NPG) xrow = (nl == 0) ? (ctx_emb + (size_t)g*HID)
                                   : (node_emb + ((size_t)(g*NPG + nl))*HID);
  }
  const float* pA = tmp + ((size_t)(g*HID + k0 + lr))*HID;
  const float* pB = pA + (size_t)BGR*HID*HID;
  for (int h0c = 0; h0c < HID; h0c += 32){
    #pragma unroll
    for (int j=0;j<8;++j) As[lc+j][lr] = xrow ? xrow[h0c + lc + j] : 0.f;
    #pragma unroll
    for (int j=0;j<8;++j) Bs[lc+j][lr] = pA[h0c+lc+j] + pB[h0c+lc+j];
    __syncthreads();
    #pragma unroll
    for (int hc=0;hc<32;++hc){
      float a[4], b[4];
      #pragma unroll
      for (int i=0;i<4;++i) a[i] = As[hc][ty*4+i];
      #pragma unroll
      for (int j=0;j<4;++j) b[j] = Bs[hc][tx*4+j];
      #pragma unroll
      for (int i=0;i<4;++i)
        #pragma unroll
        for (int j=0;j<4;++j) acc[i][j] += a[i]*b[j];
    }
    __syncthreads();
  }
  float bb[4];
  #pragma unroll
  for (int j=0;j<4;++j) bb[j] = b_bil[k0 + tx*4 + j];
  #pragma unroll
  for (int i=0;i<4;++i){
    int nl = n0 + ty*4 + i;
    if (nl < NPG){
      float* o = nodes + ((size_t)(g*NPG + nl))*HID + k0 + tx*4;
      #pragma unroll
      for (int j=0;j<4;++j) o[j] = acc[i][j] + bb[j];
    }
  }
}

// xl = nodes @ W_gat ; as = xl.att_src ; ad = xl.att_dst (fused epilogue)
__global__ __launch_bounds__(256) void k_xl(const float* __restrict__ nodes,
                                            const float* __restrict__ W_gat,
                                            const float* __restrict__ att_src,
                                            const float* __restrict__ att_dst,
                                            float* __restrict__ xl,
                                            float* __restrict__ as_a,
                                            float* __restrict__ ad_a){
  const int n0 = blockIdx.x * 64;
  __shared__ float As[32][65];
  __shared__ float Bs[32][128];
  __shared__ float reds[64][17];
  __shared__ float redd[64][17];
  const int tid = threadIdx.x, ty = tid>>4, tx = tid&15;
  float acc[4][8] = {};
  const int ar = tid>>2, ac = (tid&3)*8;
  const int br = tid>>3, bc = (tid&7)*16;
  for (int k0=0;k0<HID;k0+=32){
    #pragma unroll
    for (int j=0;j<8;++j) As[ac+j][ar] = nodes[(size_t)(n0+ar)*HID + k0+ac+j];
    #pragma unroll
    for (int j=0;j<16;++j) Bs[br][bc+j] = W_gat[(size_t)(k0+br)*HID + bc + j];
    __syncthreads();
    #pragma unroll
    for (int kc=0;kc<32;++kc){
      float a[4], b[8];
      #pragma unroll
      for (int i=0;i<4;++i) a[i] = As[kc][ty*4+i];
      #pragma unroll
      for (int j=0;j<8;++j) b[j] = Bs[kc][tx*8+j];
      #pragma unroll
      for (int i=0;i<4;++i)
        #pragma unroll
        for (int j=0;j<8;++j) acc[i][j] += a[i]*b[j];
    }
    __syncthreads();
  }
  float asr[8], adr[8];
  #pragma unroll
  for (int j=0;j<8;++j){ asr[j]=att_src[tx*8+j]; adr[j]=att_dst[tx*8+j]; }
  #pragma unroll
  for (int i=0;i<4;++i){
    float ps=0.f, pd=0.f;
    #pragma unroll
    for (int j=0;j<8;++j){ ps += acc[i][j]*asr[j]; pd += acc[i][j]*adr[j]; }
    reds[ty*4+i][tx]=ps; redd[ty*4+i][tx]=pd;
    float4 v0 = make_float4(acc[i][0],acc[i][1],acc[i][2],acc[i][3]);
    float4 v1 = make_float4(acc[i][4],acc[i][5],acc[i][6],acc[i][7]);
    float* o = xl + (size_t)(n0+ty*4+i)*HID + tx*8;
    *(float4*)o = v0; *(float4*)(o+4) = v1;
  }
  __syncthreads();
  if (tid < 64){
    float s=0.f, d2=0.f;
    #pragma unroll
    for (int t2=0;t2<16;++t2){ s += reds[tid][t2]; d2 += redd[tid][t2]; }
    as_a[n0+tid]=s; ad_a[n0+tid]=d2;
  }
}

// per-node softmax-weighted aggregation (1 wave per node), self-loop included.
// XCD-swizzled: block b -> node group (b&7)*1002 + (b>>3), so each XCD owns
// 8 whole graphs (2 MB xl slice, L2-resident).
__global__ __launch_bounds__(256) void k_agg(const float* __restrict__ xl,
                                             const float* __restrict__ as_a,
                                             const float* __restrict__ ad_a,
                                             const float* __restrict__ aself,
                                             const int* __restrict__ off,
                                             const int* __restrict__ deg,
                                             const int* __restrict__ csr_src,
                                             const float* __restrict__ csr_aed,
                                             const float* __restrict__ gbias,
                                             float* __restrict__ nodes){
  const int lane = threadIdx.x & 63;
  const int nb = blockIdx.x;                       // 0..8015
  const int idx = (nb & 7)*1002 + (nb >> 3);       // XCD-local group
  const int n = idx*4 + (threadIdx.x >> 6);
  if (n >= NN) return;
  const int o = off[n], d = deg[n];
  const float ad_n = ad_a[n];
  float a_self = as_a[n] + ad_n + aself[n];
  a_self = a_self > 0.f ? a_self : a_self*NEG;
  // pass 1: online max/sum of exp over in-edges (strided across lanes)
  float m = -1e30f, s = 0.f;
  for (int i = lane; i < d; i += 64){
    int si = csr_src[o+i];
    float a = as_a[si] + ad_n + csr_aed[o+i];
    a = a > 0.f ? a : a*NEG;
    if (a > m){ s = s*__expf(m - a) + 1.f; m = a; }
    else s += __expf(a - m);
  }
  #pragma unroll
  for (int w=32; w>=1; w>>=1){
    float mo = __shfl_xor(m, w);
    float so = __shfl_xor(s, w);
    float M = fmaxf(m, mo);
    s = s*__expf(m - M) + so*__expf(mo - M);
    m = M;
  }
  { float M = fmaxf(m, a_self);
    s = s*__expf(m - M) + __expf(a_self - M);
    m = M; }
  const float inv = 1.f / s;
  // pass 2: chunked — each lane computes w for ONE edge, then shuffle-broadcast
  float accx = 0.f, accy = 0.f;
  const float* xlane = xl + lane*2;
  for (int c = 0; c < d; c += 64){
    int i = c + lane;
    float w = 0.f; int si = 0;
    if (i < d){
      si = csr_src[o+i];
      float a = as_a[si] + ad_n + csr_aed[o+i];
      a = a > 0.f ? a : a*NEG;
      w = __expf(a - m)*inv;
    }
    const int cnt = (d - c) < 64 ? (d - c) : 64;
    int j = 0;
    for (; j + 4 <= cnt; j += 4){
      int   s0 = __shfl(si, j),   s1 = __shfl(si, j+1),
            s2 = __shfl(si, j+2), s3 = __shfl(si, j+3);
      float w0 = __shfl(w, j),    w1 = __shfl(w, j+1),
            w2 = __shfl(w, j+2),  w3 = __shfl(w, j+3);
      float2 v0 = *(const float2*)(xlane + (size_t)s0*HID);
      float2 v1 = *(const float2*)(xlane + (size_t)s1*HID);
      float2 v2 = *(const float2*)(xlane + (size_t)s2*HID);
      float2 v3 = *(const float2*)(xlane + (size_t)s3*HID);
      accx += w0*v0.x + w1*v1.x + w2*v2.x + w3*v3.x;
      accy += w0*v0.y + w1*v1.y + w2*v2.y + w3*v3.y;
    }
    for (; j < cnt; ++j){
      int   sj = __shfl(si, j);
      float wj = __shfl(w, j);
      float2 v = *(const float2*)(xlane + (size_t)sj*HID);
      accx += wj*v.x; accy += wj*v.y;
    }
  }
  { float w = __expf(a_self - m)*inv;
    const float2 v = *(const float2*)(xlane + (size_t)n*HID);
    accx += w*v.x; accy += w*v.y; }
  float2 ov;
  ov.x = accx + gbias[lane*2];
  ov.y = accy + gbias[lane*2+1];
  *(float2*)(nodes + (size_t)n*HID + lane*2) = ov;
}

__global__ void k_out(const float* __restrict__ nodes, const int* __restrict__ ctxn,
                      float* __restrict__ out){
  int b = blockIdx.x, h = threadIdx.x;
  out[b*HID + h] = nodes[(size_t)ctxn[b]*HID + h];
}

extern "C" void kernel_launch(void* const* d_in, const int* in_sizes, int n_in,
                              void* d_out, int out_size, void* d_ws, size_t ws_size,
                              hipStream_t stream){
  (void)n_in; (void)out_size; (void)ws_size;
  const float* lm       = (const float*)d_in[0];
  const float* node_emb = (const float*)d_in[1];
  const int*   eidx     = (const int*)d_in[2];
  const int*   etype    = (const int*)d_in[3];
  const int*   ctxn     = (const int*)d_in[4];
  const float* W_lm     = (const float*)d_in[5];
  const float* b_lm     = (const float*)d_in[6];
  const float* W_bil    = (const float*)d_in[7];
  const float* b_bil    = (const float*)d_in[8];
  const float* etab     = (const float*)d_in[9];
  const float* W_gat    = (const float*)d_in[10];
  const float* att_src  = (const float*)d_in[11];
  const float* att_dst  = (const float*)d_in[12];
  const float* W_edge   = (const float*)d_in[13];
  const float* att_edge = (const float*)d_in[14];
  const float* gbias    = (const float*)d_in[15];
  const int E = in_sizes[3];
  const int* src = eidx;
  const int* dst = eidx + E;

  char* p = (char*)d_ws;
  auto take = [&](size_t nbytes){ void* r = (void*)p; p += (nbytes + 255) & ~(size_t)255; return r; };
  float* nodes   = (float*)take((size_t)NN*HID*4);
  float* xl      = (float*)take((size_t)NN*HID*4);
  float* tmp     = (float*)take((size_t)2*BGR*HID*HID*4);
  float* ctx_emb = (float*)take((size_t)BGR*HID*4);
  float* as_a    = (float*)take((size_t)NN*4);
  float* ad_a    = (float*)take((size_t)NN*4);
  float* aself   = (float*)take((size_t)NN*4);
  float* asum    = (float*)take((size_t)NN*4);
  int*   deg     = (int*)take((size_t)NN*4);
  int*   off     = (int*)take((size_t)NN*4);
  int*   cursor  = (int*)take((size_t)NN*4);
  int*   counter = (int*)take(256);
  float* te      = (float*)take(256);
  int*   csr_src = (int*)take((size_t)E*4);
  float* csr_aed = (float*)take((size_t)E*4);

  k_pre<<<1,128,0,stream>>>(W_edge, att_edge, etab, te);
  k_ctx<<<BGR,HID,0,stream>>>(lm, W_lm, b_lm, ctx_emb);
  k_zero<<<(NN+255)/256,256,0,stream>>>(deg, asum, counter);
  k_count<<<(E+255)/256,256,0,stream>>>(dst, etype, te, deg, asum, E);
  k_offsets<<<(NN+255)/256,256,0,stream>>>(deg, asum, off, cursor, aself, counter);
  k_fill<<<(E+255)/256,256,0,stream>>>(src, dst, etype, te, cursor, csr_src, csr_aed, E);
  k_tmp<<<512,256,0,stream>>>(lm, W_bil, tmp);
  k_apply<<<BGR*16,256,0,stream>>>(node_emb, ctx_emb, tmp, b_bil, nodes);
  for (int h=0; h<3; ++h){
    k_xl<<<NN/64,256,0,stream>>>(nodes, W_gat, att_src, att_dst, xl, as_a, ad_a);
    k_agg<<<NN/4,256,0,stream>>>(xl, as_a, ad_a, aself, off, deg, csr_src, csr_aed, gbias, nodes);
  }
  k_out<<<BGR,HID,0,stream>>>(nodes, ctxn, (float*)d_out);
}